// Round 1
// baseline (1105.663 us; speedup 1.0000x reference)
//
#include <hip/hip_runtime.h>
#include <math.h>

// Problem constants (fixed by setup_inputs)
#define M_TOK 16384   // B*T = 8*2048
#define DIM   256     // D
#define VOC   8192    // V

// argmin GEMM tiling
#define TM 64
#define TN 128
#define KC 32
#define VHALF 4096    // V split in 2 halves -> 512 blocks = 2 blocks/CU

// workspace layout (float element offsets)
#define WS_XSQ    0                         // [16384]
#define WS_ESQ    16384                     // [8192]
#define WS_CANDV  24576                     // [2][16384]
#define WS_CANDI  57344                     // [2][16384] (int)
#define WS_COUNTS 90112                     // [8192]
#define WS_SUMS   98304                     // [8192*256]
#define WS_ZERO_OFF_BYTES (WS_COUNTS * 4)
#define WS_ZERO_BYTES ((8192 + 8192 * 256) * 4)

// out layout (float element offsets): quantize, codes, new_embed, new_cluster, new_embed_avg
#define OUT_Q   0
#define OUT_C   4194304
#define OUT_NE  4210688
#define OUT_NCS 6307840
#define OUT_NEA 6316032

// ---------------------------------------------------------------------------
// K_pre: row-wise sum of squares for input [M,D] and embed [V,D].
// One wave per row; lane handles 4 contiguous floats; 64-lane butterfly sum.
__global__ __launch_bounds__(256) void rowsq_kernel(
    const float* __restrict__ x, const float* __restrict__ e,
    float* __restrict__ xsq, float* __restrict__ esq)
{
    int row  = blockIdx.x * 4 + (threadIdx.x >> 6);
    int lane = threadIdx.x & 63;
    const float* src;
    float* dst;
    int r;
    if (row < M_TOK) { src = x + (size_t)row * DIM; dst = xsq; r = row; }
    else             { r = row - M_TOK; src = e + (size_t)r * DIM; dst = esq; }
    float4 v = ((const float4*)src)[lane];
    float s = v.x * v.x + v.y * v.y + v.z * v.z + v.w * v.w;
    #pragma unroll
    for (int o = 1; o < 64; o <<= 1) s += __shfl_xor(s, o, 64);
    if (lane == 0) dst[r] = s;
}

// ---------------------------------------------------------------------------
// K1: fused GEMM + running argmin. Block: 64 tokens x 128 codes/tile over one
// V-half. Thread (tx=tid&15, ty=tid>>4) owns 4 m-rows x 8 n-cols.
// LDS tiles transposed so fragment reads are aligned ds_read_b128:
//   A-read: 4 distinct addrs/wave (16-lane broadcast); B-read split at
//   tx*4 and 64+tx*4 -> 2-way bank alias per instruction (free).
__global__ __launch_bounds__(256, 2) void argmin_kernel(
    const float* __restrict__ X, const float* __restrict__ E,
    const float* __restrict__ xsq, const float* __restrict__ esq,
    float* __restrict__ candval, int* __restrict__ candidx)
{
    __shared__ __align__(16) float Xs[KC][TM + 4];   // stride 68 floats
    __shared__ __align__(16) float Es[KC][TN + 4];   // stride 132 floats

    const int tid = threadIdx.x;
    const int tx = tid & 15;
    const int ty = tid >> 4;
    const int m0 = blockIdx.x * TM;
    const int half = blockIdx.y;
    const int vbase = half * VHALF;

    float minv[4];
    int   mini[4];
    #pragma unroll
    for (int i = 0; i < 4; ++i) { minv[i] = 3.4e38f; mini[i] = 0; }

    float xs[4];
    #pragma unroll
    for (int i = 0; i < 4; ++i) xs[i] = xsq[m0 + ty * 4 + i];

    for (int nt = 0; nt < VHALF / TN; ++nt) {
        const int n0 = vbase + nt * TN;
        float acc[4][8];
        #pragma unroll
        for (int i = 0; i < 4; ++i)
            #pragma unroll
            for (int j = 0; j < 8; ++j) acc[i][j] = 0.0f;

        for (int kc = 0; kc < DIM / KC; ++kc) {
            const int k0 = kc * KC;
            __syncthreads();   // previous chunk's reads done before overwrite
            // stage X chunk: 64 x 32 = 512 float4, 2 per thread
            #pragma unroll
            for (int i = 0; i < 2; ++i) {
                int idx4 = tid + i * 256;
                int m = idx4 >> 3;          // 8 float4 per row (KC/4)
                int kq = idx4 & 7;
                float4 v = *(const float4*)&X[(size_t)(m0 + m) * DIM + k0 + kq * 4];
                Xs[kq * 4 + 0][m] = v.x; Xs[kq * 4 + 1][m] = v.y;
                Xs[kq * 4 + 2][m] = v.z; Xs[kq * 4 + 3][m] = v.w;
            }
            // stage E chunk: 128 x 32 = 1024 float4, 4 per thread
            #pragma unroll
            for (int i = 0; i < 4; ++i) {
                int idx4 = tid + i * 256;
                int n = idx4 >> 3;
                int kq = idx4 & 7;
                float4 v = *(const float4*)&E[(size_t)(n0 + n) * DIM + k0 + kq * 4];
                Es[kq * 4 + 0][n] = v.x; Es[kq * 4 + 1][n] = v.y;
                Es[kq * 4 + 2][n] = v.z; Es[kq * 4 + 3][n] = v.w;
            }
            __syncthreads();
            #pragma unroll
            for (int kk = 0; kk < KC; ++kk) {
                float a[4], b[8];
                *(float4*)&a[0] = *(const float4*)&Xs[kk][ty * 4];
                *(float4*)&b[0] = *(const float4*)&Es[kk][tx * 4];
                *(float4*)&b[4] = *(const float4*)&Es[kk][64 + tx * 4];
                #pragma unroll
                for (int i = 0; i < 4; ++i)
                    #pragma unroll
                    for (int j = 0; j < 8; ++j)
                        acc[i][j] = fmaf(a[i], b[j], acc[i][j]);
            }
        }
        // running argmin update; index order within thread is ascending, so
        // strict < keeps the first (lowest) index on exact ties.
        #pragma unroll
        for (int j = 0; j < 8; ++j) {
            int nn = (j < 4) ? (tx * 4 + j) : (64 + tx * 4 + (j - 4));
            int gidx = n0 + nn;
            float eq = esq[gidx];
            #pragma unroll
            for (int i = 0; i < 4; ++i) {
                float d2 = (xs[i] - 2.0f * acc[i][j]) + eq;  // matches ref formula
                if (d2 < minv[i]) { minv[i] = d2; mini[i] = gidx; }
            }
        }
    }

    // reduce across the 16 lanes (same ty) sharing these m-rows; lexicographic
    // (val, idx) keeps lowest index on ties.
    #pragma unroll
    for (int o = 1; o < 16; o <<= 1) {
        #pragma unroll
        for (int i = 0; i < 4; ++i) {
            float ov = __shfl_xor(minv[i], o, 64);
            int   oi = __shfl_xor(mini[i], o, 64);
            if (ov < minv[i] || (ov == minv[i] && oi < mini[i])) {
                minv[i] = ov; mini[i] = oi;
            }
        }
    }
    if (tx == 0) {
        #pragma unroll
        for (int i = 0; i < 4; ++i) {
            int mg = m0 + ty * 4 + i;
            candval[half * M_TOK + mg] = minv[i];
            candidx[half * M_TOK + mg] = mini[i];
        }
    }
}

// ---------------------------------------------------------------------------
// K2: merge the two V-half candidates, write codes (+as float) and the
// straight-through quantize output, scatter counts/sums via fp32 atomics.
__global__ __launch_bounds__(256) void assign_kernel(
    const float* __restrict__ X, const float* __restrict__ E,
    const float* __restrict__ candval, const int* __restrict__ candidx,
    float* __restrict__ out_q, float* __restrict__ out_codes,
    float* __restrict__ counts, float* __restrict__ sums)
{
    int t = blockIdx.x * 4 + (threadIdx.x >> 6);
    int lane = threadIdx.x & 63;
    float v0 = candval[t], v1 = candval[M_TOK + t];
    int   i0 = candidx[t], i1 = candidx[M_TOK + t];
    // half 0 holds the lower indices -> tie goes to i0 (first occurrence)
    int code = (v1 < v0) ? i1 : i0;
    if (lane == 0) {
        out_codes[t] = (float)code;
        atomicAdd(&counts[code], 1.0f);
    }
    float4 x = *(const float4*)&X[(size_t)t * DIM + lane * 4];
    float4 e = *(const float4*)&E[(size_t)code * DIM + lane * 4];
    float4 q;
    q.x = x.x + (e.x - x.x);   // replicate STE arithmetic exactly
    q.y = x.y + (e.y - x.y);
    q.z = x.z + (e.z - x.z);
    q.w = x.w + (e.w - x.w);
    *(float4*)&out_q[(size_t)t * DIM + lane * 4] = q;
    float* s = &sums[(size_t)code * DIM + lane * 4];
    atomicAdd(s + 0, x.x);
    atomicAdd(s + 1, x.y);
    atomicAdd(s + 2, x.z);
    atomicAdd(s + 3, x.w);
}

// ---------------------------------------------------------------------------
// K3: EMA finalize. new_cs = cs*0.99 + cnt*0.01; codebook = sum/T;
// new_ea = ea*0.99 + codebook*0.01; new_embed = new_ea / (new_cs + eps).
__global__ __launch_bounds__(256) void finalize_kernel(
    const float* __restrict__ cs, const float* __restrict__ ea,
    const float* __restrict__ counts, const float* __restrict__ sums,
    float* __restrict__ out_embed, float* __restrict__ out_cs,
    float* __restrict__ out_ea)
{
    int vd = blockIdx.x * 256 + threadIdx.x;
    int v = vd >> 8, d = vd & 255;
    float cnt = counts[v];
    float ncs = cs[v] * 0.99f + cnt * 0.01f;
    float cb  = sums[vd] * (1.0f / 2048.0f);
    float nea = ea[vd] * 0.99f + cb * 0.01f;
    out_ea[vd] = nea;
    out_embed[vd] = nea / (ncs + 1e-5f);
    if (d == 0) out_cs[v] = ncs;
}

// ---------------------------------------------------------------------------
extern "C" void kernel_launch(void* const* d_in, const int* in_sizes, int n_in,
                              void* d_out, int out_size, void* d_ws, size_t ws_size,
                              hipStream_t stream)
{
    const float* input     = (const float*)d_in[0];   // [8,2048,256]
    const float* embed     = (const float*)d_in[1];   // [8192,256]
    const float* cluster   = (const float*)d_in[2];   // [8192]
    const float* embed_avg = (const float*)d_in[3];   // [8192,256]

    float* out = (float*)d_out;
    float* ws  = (float*)d_ws;

    float* xsq     = ws + WS_XSQ;
    float* esq     = ws + WS_ESQ;
    float* candval = ws + WS_CANDV;
    int*   candidx = (int*)(ws + WS_CANDI);
    float* counts  = ws + WS_COUNTS;
    float* sums    = ws + WS_SUMS;

    // zero the atomic accumulators (ws is poisoned 0xAA before every launch)
    hipMemsetAsync((char*)d_ws + WS_ZERO_OFF_BYTES, 0, WS_ZERO_BYTES, stream);

    rowsq_kernel<<<(M_TOK + VOC) / 4, 256, 0, stream>>>(input, embed, xsq, esq);

    dim3 grid1(M_TOK / TM, 2);
    argmin_kernel<<<grid1, 256, 0, stream>>>(input, embed, xsq, esq, candval, candidx);

    assign_kernel<<<M_TOK / 4, 256, 0, stream>>>(
        input, embed, candval, candidx,
        out + OUT_Q, out + OUT_C, counts, sums);

    finalize_kernel<<<(VOC * DIM) / 256, 256, 0, stream>>>(
        cluster, embed_avg, counts, sums,
        out + OUT_NE, out + OUT_NCS, out + OUT_NEA);
}

// Round 2
// 661.974 us; speedup vs baseline: 1.6703x; 1.6703x over previous
//
#include <hip/hip_runtime.h>
#include <math.h>

// Problem constants (fixed by setup_inputs)
#define M_TOK 16384   // B*T
#define DIM   256     // D (=K)
#define VOC   8192    // V (=N)

// GEMM tiling
#define BM 128
#define BN 128
#define BK 32
#define NBLK_N (VOC / BN)   // 64
#define GAP_EPS 0.01f       // rescue trigger; split-bf16 d2 err ~1e-4 << 0.01

typedef unsigned short u16;
typedef __attribute__((ext_vector_type(8))) __bf16 bf16x8;
typedef __attribute__((ext_vector_type(4))) float f32x4;

// ---- workspace layout (float-element offsets) ------------------------------
#define WS_ESQ      0                     // [8192]
#define WS_CODESI   8192                  // [16384] int
#define WS_FLAGROWS 24576                 // [16384] int
#define WS_CANDV    40960                 // [64][16384] f32
#define WS_CANDI    1089536               // [64][16384] int
#define WS_CANDS    2138112               // [64][16384] f32
#define WS_XHI      3186688               // [16384*256] bf16 (2097152 f32 slots)
#define WS_XLO      5283840
#define WS_EHI      7380992               // [8192*256] bf16 (1048576 slots)
#define WS_ELO      8429568
#define WS_COUNTS   9478144               // [8192]
#define WS_SUMS     9486336               // [8192*256]
#define WS_FLAGCNT  11583488              // [16] int
#define WS_ZERO_OFF_BYTES ((size_t)WS_COUNTS * 4)
#define WS_ZERO_BYTES     ((size_t)(8192 + 2097152 + 16) * 4)

// ---- out layout (float-element offsets): quantize, codes, new_embed, new_cs, new_ea
#define OUT_Q   0
#define OUT_C   4194304
#define OUT_NE  4210688
#define OUT_NCS 6307840
#define OUT_NEA 6316032

__device__ inline u16 f2bf_rn(float x) {
    unsigned u = __float_as_uint(x);
    unsigned r = u + 0x7FFFu + ((u >> 16) & 1u);   // round-to-nearest-even
    return (u16)(r >> 16);
}
__device__ inline float bf2f(u16 u) { return __uint_as_float(((unsigned)u) << 16); }

// ---------------------------------------------------------------------------
// prep: split X,E into bf16 hi/lo; compute esq from fp32 originals.
__global__ __launch_bounds__(256) void prep_kernel(
    const float* __restrict__ X, const float* __restrict__ E,
    u16* __restrict__ Xhi, u16* __restrict__ Xlo,
    u16* __restrict__ Ehi, u16* __restrict__ Elo,
    float* __restrict__ esq)
{
    int row  = blockIdx.x * 4 + (threadIdx.x >> 6);
    int lane = threadIdx.x & 63;
    bool isX = row < M_TOK;
    int r = isX ? row : row - M_TOK;
    const float* src = isX ? X + (size_t)row * DIM : E + (size_t)r * DIM;
    float4 v = ((const float4*)src)[lane];

    ushort4 h, lo;
    {
        u16 hb = f2bf_rn(v.x); h.x = hb; lo.x = f2bf_rn(v.x - bf2f(hb));
        hb = f2bf_rn(v.y); h.y = hb; lo.y = f2bf_rn(v.y - bf2f(hb));
        hb = f2bf_rn(v.z); h.z = hb; lo.z = f2bf_rn(v.z - bf2f(hb));
        hb = f2bf_rn(v.w); h.w = hb; lo.w = f2bf_rn(v.w - bf2f(hb));
    }
    u16* dh = isX ? Xhi : Ehi;
    u16* dl = isX ? Xlo : Elo;
    *(ushort4*)&dh[(size_t)r * DIM + lane * 4] = h;
    *(ushort4*)&dl[(size_t)r * DIM + lane * 4] = lo;

    if (!isX) {
        float s = v.x * v.x + v.y * v.y + v.z * v.z + v.w * v.w;
        #pragma unroll
        for (int o = 1; o < 64; o <<= 1) s += __shfl_xor(s, o, 64);
        if (lane == 0) esq[r] = s;
    }
}

// ---------------------------------------------------------------------------
// mfma_argmin: per 128x128 tile, dot = hi*hi + lo*hi + hi*lo (3 MFMAs per
// fragment pair), epilogue tracks per-row top-2 of (esq[n] - 2*dot), writes
// per-(row, n-block) candidates (best val, best idx, second val).
//
// LDS tiles staged by global_load_lds(16B): physical chunk p of row r holds
// global 16B-chunk p ^ ((r>>1)&3); readers XOR the same swizzle. This keeps
// frag ds_read_b128 at <=2-way bank aliasing (free) despite the DMA's
// forced unpadded row stride of 64B.
__global__ __launch_bounds__(256, 2) void mfma_argmin_kernel(
    const u16* __restrict__ Xhi, const u16* __restrict__ Xlo,
    const u16* __restrict__ Ehi, const u16* __restrict__ Elo,
    const float* __restrict__ esq,
    float* __restrict__ candV, int* __restrict__ candI, float* __restrict__ candS)
{
    __shared__ __align__(16) char tiles[4 * 8192];   // Ahi, Alo, Bhi, Blo
    __shared__ float smB[2][128];
    __shared__ int   smI[2][128];
    __shared__ float smS[2][128];

    const int tid = threadIdx.x;
    const int w = tid >> 6, l = tid & 63;
    const int wy = w >> 1, wx = w & 1;
    const int m0 = blockIdx.x * BM;
    const int n0 = blockIdx.y * BN;

    f32x4 acc[4][4];
    #pragma unroll
    for (int i = 0; i < 4; ++i)
        #pragma unroll
        for (int j = 0; j < 4; ++j) acc[i][j] = (f32x4)0.0f;

    // ---- staging setup: wave w stages tile w (0=Ahi 1=Alo 2=Bhi 3=Blo)
    const u16* gbase;
    int row0;
    if (w == 0)      { gbase = Xhi; row0 = m0; }
    else if (w == 1) { gbase = Xlo; row0 = m0; }
    else if (w == 2) { gbase = Ehi; row0 = n0; }
    else             { gbase = Elo; row0 = n0; }
    const int swz_c = (l & 3) ^ ((l >> 3) & 3);   // lane-constant chunk swizzle
    const u16* gsrc0 = gbase + (size_t)(row0 + (l >> 2)) * DIM + swz_c * 8;
    char* ltile = tiles + w * 8192;

    // ---- fragment read addresses (loop-invariant)
    const int frow = l & 15, fq = l >> 4;
    const int fs = ((fq ^ ((frow >> 1) & 3)) * 16);
    const char* aHiP = tiles + 0 * 8192 + (wy * 64 + frow) * 64 + fs;
    const char* aLoP = tiles + 1 * 8192 + (wy * 64 + frow) * 64 + fs;
    const char* bHiP = tiles + 2 * 8192 + (wx * 64 + frow) * 64 + fs;
    const char* bLoP = tiles + 3 * 8192 + (wx * 64 + frow) * 64 + fs;

    for (int ks = 0; ks < DIM / BK; ++ks) {
        const int k0 = ks * BK;
        __syncthreads();   // prev iter's frag reads done before DMA overwrite
        #pragma unroll
        for (int i = 0; i < 8; ++i) {
            __builtin_amdgcn_global_load_lds(
                (const __attribute__((address_space(1))) unsigned int*)(gsrc0 + (size_t)i * 16 * DIM + k0),
                (__attribute__((address_space(3))) unsigned int*)(ltile + i * 1024),
                16, 0, 0);
        }
        __syncthreads();   // barrier drains vmcnt (compiler-emitted)

        bf16x8 ah[4], al[4];
        #pragma unroll
        for (int mt = 0; mt < 4; ++mt) {
            ah[mt] = *(const bf16x8*)(aHiP + mt * 1024);
            al[mt] = *(const bf16x8*)(aLoP + mt * 1024);
        }
        #pragma unroll
        for (int nt = 0; nt < 4; ++nt) {
            bf16x8 bh = *(const bf16x8*)(bHiP + nt * 1024);
            bf16x8 bl = *(const bf16x8*)(bLoP + nt * 1024);
            #pragma unroll
            for (int mt = 0; mt < 4; ++mt) {
                acc[mt][nt] = __builtin_amdgcn_mfma_f32_16x16x32_bf16(ah[mt], bh, acc[mt][nt], 0, 0, 0);
                acc[mt][nt] = __builtin_amdgcn_mfma_f32_16x16x32_bf16(al[mt], bh, acc[mt][nt], 0, 0, 0);
                acc[mt][nt] = __builtin_amdgcn_mfma_f32_16x16x32_bf16(ah[mt], bl, acc[mt][nt], 0, 0, 0);
            }
        }
    }

    // ---- epilogue: per-row top-2 argmin of val = esq[n] - 2*dot
    float eq[4];
    #pragma unroll
    for (int nt = 0; nt < 4; ++nt) eq[nt] = esq[n0 + wx * 64 + nt * 16 + frow];

    #pragma unroll
    for (int mt = 0; mt < 4; ++mt) {
        #pragma unroll
        for (int r = 0; r < 4; ++r) {
            float b = 3.4e38f, s = 3.4e38f;
            int bi = 0;
            #pragma unroll
            for (int nt = 0; nt < 4; ++nt) {
                float v = fmaf(-2.0f, acc[mt][nt][r], eq[nt]);
                int col = n0 + wx * 64 + nt * 16 + frow;
                if (v < b) { s = b; b = v; bi = col; }
                else if (v < s) s = v;
            }
            // lexicographic top-2 butterfly over the 16 lanes sharing rows
            #pragma unroll
            for (int o = 1; o < 16; o <<= 1) {
                float ob = __shfl_xor(b, o, 64);
                int   oi = __shfl_xor(bi, o, 64);
                float os = __shfl_xor(s, o, 64);
                bool take = (ob < b) || (ob == b && oi < bi);
                float keep = take ? b : ob;
                b  = take ? ob : b;
                bi = take ? oi : bi;
                s  = fminf(fminf(s, os), keep);
            }
            if (frow == 0) {
                int m_loc = wy * 64 + mt * 16 + fq * 4 + r;
                smB[wx][m_loc] = b; smI[wx][m_loc] = bi; smS[wx][m_loc] = s;
            }
        }
    }
    __syncthreads();
    if (tid < 128) {
        float b0 = smB[0][tid], b1 = smB[1][tid];
        int   i0 = smI[0][tid], i1 = smI[1][tid];
        float s0 = smS[0][tid], s1 = smS[1][tid];
        bool take = (b1 < b0);                 // tie -> wave 0 (lower cols)
        float b = take ? b1 : b0;
        int  bi = take ? i1 : i0;
        float s = fminf(fminf(s0, s1), take ? b0 : b1);
        size_t e = (size_t)blockIdx.y * M_TOK + (m0 + tid);
        candV[e] = b; candI[e] = bi; candS[e] = s;
    }
}

// ---------------------------------------------------------------------------
// reduce: fold 64 n-block candidates per row (ascending n -> first-min tie),
// write codes; flag rows whose global top-2 gap < GAP_EPS for fp32 rescue.
__global__ __launch_bounds__(256) void reduce_kernel(
    const float* __restrict__ candV, const int* __restrict__ candI,
    const float* __restrict__ candS,
    int* __restrict__ codesI, float* __restrict__ codesF,
    int* __restrict__ flagCnt, int* __restrict__ flagRows)
{
    int row = blockIdx.x * 256 + threadIdx.x;
    float best = 3.4e38f, second = 3.4e38f;
    int bi = 0;
    for (int e = 0; e < NBLK_N; ++e) {
        size_t o = (size_t)e * M_TOK + row;
        float v = candV[o];
        if (v < best) {
            second = fminf(best, candS[o]);
            best = v; bi = candI[o];
        } else {
            second = fminf(second, v);
        }
    }
    codesI[row] = bi;
    codesF[row] = (float)bi;
    if (second - best < GAP_EPS) {
        int k = atomicAdd(flagCnt, 1);
        flagRows[k] = row;
    }
}

// ---------------------------------------------------------------------------
// rescue: exact fp32 argmin over all codes for flagged rows only.
__global__ __launch_bounds__(256) void rescue_kernel(
    const float* __restrict__ X, const float* __restrict__ E,
    const float* __restrict__ esq,
    int* __restrict__ codesI, float* __restrict__ codesF,
    const int* __restrict__ flagCnt, const int* __restrict__ flagRows)
{
    __shared__ float xr[DIM];
    __shared__ float rv[4];
    __shared__ int   ri[4];
    const int nf = flagCnt[0];
    const int lane = threadIdx.x & 63, wv = threadIdx.x >> 6;

    for (int f = blockIdx.x; f < nf; f += gridDim.x) {
        int row = flagRows[f];
        __syncthreads();
        xr[threadIdx.x] = X[(size_t)row * DIM + threadIdx.x];
        __syncthreads();
        float best = 3.4e38f; int bi = 0;
        for (int c = threadIdx.x; c < VOC; c += 256) {
            const float4* er = (const float4*)(E + (size_t)c * DIM);
            float dot = 0.0f;
            #pragma unroll 8
            for (int k = 0; k < DIM / 4; ++k) {
                float4 e4 = er[k];
                float4 x4 = *(const float4*)&xr[k * 4];
                dot = fmaf(x4.x, e4.x, dot);
                dot = fmaf(x4.y, e4.y, dot);
                dot = fmaf(x4.z, e4.z, dot);
                dot = fmaf(x4.w, e4.w, dot);
            }
            float v = esq[c] - 2.0f * dot;
            if (v < best) { best = v; bi = c; }   // c ascending within thread
        }
        #pragma unroll
        for (int o = 1; o < 64; o <<= 1) {
            float ov = __shfl_xor(best, o, 64);
            int   oi = __shfl_xor(bi, o, 64);
            if (ov < best || (ov == best && oi < bi)) { best = ov; bi = oi; }
        }
        if (lane == 0) { rv[wv] = best; ri[wv] = bi; }
        __syncthreads();
        if (threadIdx.x == 0) {
            float b = rv[0]; int i0 = ri[0];
            for (int j = 1; j < 4; ++j)
                if (rv[j] < b || (rv[j] == b && ri[j] < i0)) { b = rv[j]; i0 = ri[j]; }
            codesI[row] = i0; codesF[row] = (float)i0;
        }
        __syncthreads();
    }
}

// ---------------------------------------------------------------------------
// assign: gather quantize + STE, scatter counts/sums via fp32 atomics.
__global__ __launch_bounds__(256) void assign_kernel(
    const float* __restrict__ X, const float* __restrict__ E,
    const int* __restrict__ codesI,
    float* __restrict__ out_q,
    float* __restrict__ counts, float* __restrict__ sums)
{
    int t = blockIdx.x * 4 + (threadIdx.x >> 6);
    int lane = threadIdx.x & 63;
    int code = codesI[t];
    if (lane == 0) atomicAdd(&counts[code], 1.0f);
    float4 x = *(const float4*)&X[(size_t)t * DIM + lane * 4];
    float4 e = *(const float4*)&E[(size_t)code * DIM + lane * 4];
    float4 q;
    q.x = x.x + (e.x - x.x);
    q.y = x.y + (e.y - x.y);
    q.z = x.z + (e.z - x.z);
    q.w = x.w + (e.w - x.w);
    *(float4*)&out_q[(size_t)t * DIM + lane * 4] = q;
    float* s = &sums[(size_t)code * DIM + lane * 4];
    atomicAdd(s + 0, x.x);
    atomicAdd(s + 1, x.y);
    atomicAdd(s + 2, x.z);
    atomicAdd(s + 3, x.w);
}

// ---------------------------------------------------------------------------
__global__ __launch_bounds__(256) void finalize_kernel(
    const float* __restrict__ cs, const float* __restrict__ ea,
    const float* __restrict__ counts, const float* __restrict__ sums,
    float* __restrict__ out_embed, float* __restrict__ out_cs,
    float* __restrict__ out_ea)
{
    int vd = blockIdx.x * 256 + threadIdx.x;
    int v = vd >> 8, d = vd & 255;
    float cnt = counts[v];
    float ncs = cs[v] * 0.99f + cnt * 0.01f;
    float cb  = sums[vd] * (1.0f / 2048.0f);
    float nea = ea[vd] * 0.99f + cb * 0.01f;
    out_ea[vd] = nea;
    out_embed[vd] = nea / (ncs + 1e-5f);
    if (d == 0) out_cs[v] = ncs;
}

// ---------------------------------------------------------------------------
extern "C" void kernel_launch(void* const* d_in, const int* in_sizes, int n_in,
                              void* d_out, int out_size, void* d_ws, size_t ws_size,
                              hipStream_t stream)
{
    const float* input     = (const float*)d_in[0];
    const float* embed     = (const float*)d_in[1];
    const float* cluster   = (const float*)d_in[2];
    const float* embed_avg = (const float*)d_in[3];

    float* out = (float*)d_out;
    float* ws  = (float*)d_ws;

    float* esq      = ws + WS_ESQ;
    int*   codesI   = (int*)(ws + WS_CODESI);
    int*   flagRows = (int*)(ws + WS_FLAGROWS);
    float* candV    = ws + WS_CANDV;
    int*   candI    = (int*)(ws + WS_CANDI);
    float* candS    = ws + WS_CANDS;
    u16*   Xhi      = (u16*)(ws + WS_XHI);
    u16*   Xlo      = (u16*)(ws + WS_XLO);
    u16*   Ehi      = (u16*)(ws + WS_EHI);
    u16*   Elo      = (u16*)(ws + WS_ELO);
    float* counts   = ws + WS_COUNTS;
    float* sums     = ws + WS_SUMS;
    int*   flagCnt  = (int*)(ws + WS_FLAGCNT);

    hipMemsetAsync((char*)d_ws + WS_ZERO_OFF_BYTES, 0, WS_ZERO_BYTES, stream);

    prep_kernel<<<(M_TOK + VOC) / 4, 256, 0, stream>>>(
        input, embed, Xhi, Xlo, Ehi, Elo, esq);

    dim3 g1(M_TOK / BM, VOC / BN);
    mfma_argmin_kernel<<<g1, 256, 0, stream>>>(
        Xhi, Xlo, Ehi, Elo, esq, candV, candI, candS);

    reduce_kernel<<<M_TOK / 256, 256, 0, stream>>>(
        candV, candI, candS, codesI, out + OUT_C, flagCnt, flagRows);

    rescue_kernel<<<32, 256, 0, stream>>>(
        input, embed, esq, codesI, out + OUT_C, flagCnt, flagRows);

    assign_kernel<<<M_TOK / 4, 256, 0, stream>>>(
        input, embed, codesI, out + OUT_Q, counts, sums);

    finalize_kernel<<<(VOC * DIM) / 256, 256, 0, stream>>>(
        cluster, embed_avg, counts, sums,
        out + OUT_NE, out + OUT_NCS, out + OUT_NEA);
}

// Round 3
// 449.884 us; speedup vs baseline: 2.4577x; 1.4714x over previous
//
#include <hip/hip_runtime.h>
#include <math.h>

// Problem constants (fixed by setup_inputs)
#define M_TOK 16384   // B*T
#define DIM   256     // D (=K)
#define VOC   8192    // V (=N)

// GEMM tiling
#define BM 128
#define BN 128
#define BK 32
#define NBLK_N (VOC / BN)   // 64
#define GAP_EPS 0.01f       // rescue trigger; split-bf16 d2 err ~1e-4 << 0.01

typedef unsigned short u16;
typedef unsigned long long u64;
typedef __attribute__((ext_vector_type(8))) __bf16 bf16x8;
typedef __attribute__((ext_vector_type(4))) float f32x4;

// ---- workspace layout (float-element offsets) ------------------------------
#define WS_ESQ      0                     // [8192]
#define WS_CODESI   8192                  // [16384] int
#define WS_FLAGROWS 24576                 // [16384] int
#define WS_CANDV    40960                 // [64][16384] f32
#define WS_CANDI    1089536               // [64][16384] int
#define WS_CANDS    2138112               // [64][16384] f32
#define WS_XHI      3186688               // [16384*256] bf16 (2097152 f32 slots)
#define WS_XLO      5283840
#define WS_EHI      7380992               // [8192*256] bf16 (1048576 slots)
#define WS_ELO      8429568
#define WS_COUNTS   9478144               // [8192]
#define WS_SUMS     9486336               // [8192*256]
#define WS_FLAGCNT  11583488              // [16] int
// rescueBuf [16384] u64 aliases Xhi (dead after mfma_argmin; reduce inits it)
#define WS_RESCUE   WS_XHI
#define WS_ZERO_OFF_BYTES ((size_t)WS_COUNTS * 4)
#define WS_ZERO_BYTES     ((size_t)(8192 + 2097152 + 16) * 4)

// ---- out layout (float-element offsets): quantize, codes, new_embed, new_cs, new_ea
#define OUT_Q   0
#define OUT_C   4194304
#define OUT_NE  4210688
#define OUT_NCS 6307840
#define OUT_NEA 6316032

__device__ inline u16 f2bf_rn(float x) {
    unsigned u = __float_as_uint(x);
    unsigned r = u + 0x7FFFu + ((u >> 16) & 1u);   // round-to-nearest-even
    return (u16)(r >> 16);
}
__device__ inline float bf2f(u16 u) { return __uint_as_float(((unsigned)u) << 16); }
__device__ inline unsigned f2key(float f) {          // order-preserving uint
    unsigned b = __float_as_uint(f);
    return (b & 0x80000000u) ? ~b : (b | 0x80000000u);
}

// ---------------------------------------------------------------------------
// prep: split X,E into bf16 hi/lo; compute esq from fp32 originals.
__global__ __launch_bounds__(256) void prep_kernel(
    const float* __restrict__ X, const float* __restrict__ E,
    u16* __restrict__ Xhi, u16* __restrict__ Xlo,
    u16* __restrict__ Ehi, u16* __restrict__ Elo,
    float* __restrict__ esq)
{
    int row  = blockIdx.x * 4 + (threadIdx.x >> 6);
    int lane = threadIdx.x & 63;
    bool isX = row < M_TOK;
    int r = isX ? row : row - M_TOK;
    const float* src = isX ? X + (size_t)row * DIM : E + (size_t)r * DIM;
    float4 v = ((const float4*)src)[lane];

    ushort4 h, lo;
    {
        u16 hb = f2bf_rn(v.x); h.x = hb; lo.x = f2bf_rn(v.x - bf2f(hb));
        hb = f2bf_rn(v.y); h.y = hb; lo.y = f2bf_rn(v.y - bf2f(hb));
        hb = f2bf_rn(v.z); h.z = hb; lo.z = f2bf_rn(v.z - bf2f(hb));
        hb = f2bf_rn(v.w); h.w = hb; lo.w = f2bf_rn(v.w - bf2f(hb));
    }
    u16* dh = isX ? Xhi : Ehi;
    u16* dl = isX ? Xlo : Elo;
    *(ushort4*)&dh[(size_t)r * DIM + lane * 4] = h;
    *(ushort4*)&dl[(size_t)r * DIM + lane * 4] = lo;

    if (!isX) {
        float s = v.x * v.x + v.y * v.y + v.z * v.z + v.w * v.w;
        #pragma unroll
        for (int o = 1; o < 64; o <<= 1) s += __shfl_xor(s, o, 64);
        if (lane == 0) esq[r] = s;
    }
}

// ---------------------------------------------------------------------------
// mfma_argmin: per 128x128 tile, dot = hi*hi + lo*hi + hi*lo (3 MFMAs per
// fragment pair), epilogue tracks per-row top-2 of (esq[n] - 2*dot).
// LDS staged via global_load_lds(16B) with XOR chunk swizzle (DMA forbids
// padding; swizzle keeps frag ds_read_b128 at <=2-way bank alias = free).
__global__ __launch_bounds__(256, 2) void mfma_argmin_kernel(
    const u16* __restrict__ Xhi, const u16* __restrict__ Xlo,
    const u16* __restrict__ Ehi, const u16* __restrict__ Elo,
    const float* __restrict__ esq,
    float* __restrict__ candV, int* __restrict__ candI, float* __restrict__ candS)
{
    __shared__ __align__(16) char tiles[4 * 8192];   // Ahi, Alo, Bhi, Blo
    __shared__ float smB[2][128];
    __shared__ int   smI[2][128];
    __shared__ float smS[2][128];

    const int tid = threadIdx.x;
    const int w = tid >> 6, l = tid & 63;
    const int wy = w >> 1, wx = w & 1;
    const int m0 = blockIdx.x * BM;
    const int n0 = blockIdx.y * BN;

    f32x4 acc[4][4];
    #pragma unroll
    for (int i = 0; i < 4; ++i)
        #pragma unroll
        for (int j = 0; j < 4; ++j) acc[i][j] = (f32x4)0.0f;

    // staging: wave w stages tile w (0=Ahi 1=Alo 2=Bhi 3=Blo)
    const u16* gbase;
    int row0;
    if (w == 0)      { gbase = Xhi; row0 = m0; }
    else if (w == 1) { gbase = Xlo; row0 = m0; }
    else if (w == 2) { gbase = Ehi; row0 = n0; }
    else             { gbase = Elo; row0 = n0; }
    const int swz_c = (l & 3) ^ ((l >> 3) & 3);
    const u16* gsrc0 = gbase + (size_t)(row0 + (l >> 2)) * DIM + swz_c * 8;
    char* ltile = tiles + w * 8192;

    const int frow = l & 15, fq = l >> 4;
    const int fs = ((fq ^ ((frow >> 1) & 3)) * 16);
    const char* aHiP = tiles + 0 * 8192 + (wy * 64 + frow) * 64 + fs;
    const char* aLoP = tiles + 1 * 8192 + (wy * 64 + frow) * 64 + fs;
    const char* bHiP = tiles + 2 * 8192 + (wx * 64 + frow) * 64 + fs;
    const char* bLoP = tiles + 3 * 8192 + (wx * 64 + frow) * 64 + fs;

    for (int ks = 0; ks < DIM / BK; ++ks) {
        const int k0 = ks * BK;
        __syncthreads();
        #pragma unroll
        for (int i = 0; i < 8; ++i) {
            __builtin_amdgcn_global_load_lds(
                (const __attribute__((address_space(1))) unsigned int*)(gsrc0 + (size_t)i * 16 * DIM + k0),
                (__attribute__((address_space(3))) unsigned int*)(ltile + i * 1024),
                16, 0, 0);
        }
        __syncthreads();

        bf16x8 ah[4], al[4];
        #pragma unroll
        for (int mt = 0; mt < 4; ++mt) {
            ah[mt] = *(const bf16x8*)(aHiP + mt * 1024);
            al[mt] = *(const bf16x8*)(aLoP + mt * 1024);
        }
        #pragma unroll
        for (int nt = 0; nt < 4; ++nt) {
            bf16x8 bh = *(const bf16x8*)(bHiP + nt * 1024);
            bf16x8 bl = *(const bf16x8*)(bLoP + nt * 1024);
            #pragma unroll
            for (int mt = 0; mt < 4; ++mt) {
                acc[mt][nt] = __builtin_amdgcn_mfma_f32_16x16x32_bf16(ah[mt], bh, acc[mt][nt], 0, 0, 0);
                acc[mt][nt] = __builtin_amdgcn_mfma_f32_16x16x32_bf16(al[mt], bh, acc[mt][nt], 0, 0, 0);
                acc[mt][nt] = __builtin_amdgcn_mfma_f32_16x16x32_bf16(ah[mt], bl, acc[mt][nt], 0, 0, 0);
            }
        }
    }

    // epilogue: per-row top-2 argmin of val = esq[n] - 2*dot
    float eq[4];
    #pragma unroll
    for (int nt = 0; nt < 4; ++nt) eq[nt] = esq[n0 + wx * 64 + nt * 16 + frow];

    #pragma unroll
    for (int mt = 0; mt < 4; ++mt) {
        #pragma unroll
        for (int r = 0; r < 4; ++r) {
            float b = 3.4e38f, s = 3.4e38f;
            int bi = 0;
            #pragma unroll
            for (int nt = 0; nt < 4; ++nt) {
                float v = fmaf(-2.0f, acc[mt][nt][r], eq[nt]);
                int col = n0 + wx * 64 + nt * 16 + frow;
                if (v < b) { s = b; b = v; bi = col; }
                else if (v < s) s = v;
            }
            #pragma unroll
            for (int o = 1; o < 16; o <<= 1) {
                float ob = __shfl_xor(b, o, 64);
                int   oi = __shfl_xor(bi, o, 64);
                float os = __shfl_xor(s, o, 64);
                bool take = (ob < b) || (ob == b && oi < bi);
                float keep = take ? b : ob;
                b  = take ? ob : b;
                bi = take ? oi : bi;
                s  = fminf(fminf(s, os), keep);
            }
            if (frow == 0) {
                int m_loc = wy * 64 + mt * 16 + fq * 4 + r;
                smB[wx][m_loc] = b; smI[wx][m_loc] = bi; smS[wx][m_loc] = s;
            }
        }
    }
    __syncthreads();
    if (tid < 128) {
        float b0 = smB[0][tid], b1 = smB[1][tid];
        int   i0 = smI[0][tid], i1 = smI[1][tid];
        float s0 = smS[0][tid], s1 = smS[1][tid];
        bool take = (b1 < b0);                 // tie -> wave 0 (lower cols)
        float b = take ? b1 : b0;
        int  bi = take ? i1 : i0;
        float s = fminf(fminf(s0, s1), take ? b0 : b1);
        size_t e = (size_t)blockIdx.y * M_TOK + (m0 + tid);
        candV[e] = b; candI[e] = bi; candS[e] = s;
    }
}

// ---------------------------------------------------------------------------
// reduce: fold 64 n-block candidates per row (ascending n -> first-min tie),
// write codes; flag rows with gap < GAP_EPS and init their rescue slot.
__global__ __launch_bounds__(256) void reduce_kernel(
    const float* __restrict__ candV, const int* __restrict__ candI,
    const float* __restrict__ candS,
    int* __restrict__ codesI, float* __restrict__ codesF,
    int* __restrict__ flagCnt, int* __restrict__ flagRows,
    u64* __restrict__ rescueBuf)
{
    int row = blockIdx.x * 256 + threadIdx.x;
    float best = 3.4e38f, second = 3.4e38f;
    int bi = 0;
    for (int e = 0; e < NBLK_N; ++e) {
        size_t o = (size_t)e * M_TOK + row;
        float v = candV[o];
        if (v < best) {
            second = fminf(best, candS[o]);
            best = v; bi = candI[o];
        } else {
            second = fminf(second, v);
        }
    }
    codesI[row] = bi;
    codesF[row] = (float)bi;
    if (second - best < GAP_EPS) {
        rescueBuf[row] = ~0ull;
        int k = atomicAdd(flagCnt, 1);
        flagRows[k] = row;
    }
}

// ---------------------------------------------------------------------------
// rescue: exact fp32 argmin for flagged rows, grid-parallel in the code dim.
// Work item = (flagged row, 256-code chunk); one code per thread; winner via
// u64 atomicMin on (sortable-float << 32 | code) -> lowest index on ties.
__global__ __launch_bounds__(256) void rescue_kernel(
    const float* __restrict__ X, const float* __restrict__ E,
    const float* __restrict__ esq,
    const int* __restrict__ flagCnt, const int* __restrict__ flagRows,
    u64* __restrict__ rescueBuf)
{
    __shared__ float xr[DIM];
    const int nwork = flagCnt[0] * (VOC / 256);
    for (int wk = blockIdx.x; wk < nwork; wk += gridDim.x) {
        int row = flagRows[wk >> 5];
        int c = ((wk & 31) << 8) + threadIdx.x;
        __syncthreads();   // previous iter's xr reads done
        xr[threadIdx.x] = X[(size_t)row * DIM + threadIdx.x];
        __syncthreads();
        const float4* er = (const float4*)(E + (size_t)c * DIM);
        float dot = 0.0f;
        #pragma unroll 8
        for (int k = 0; k < DIM / 4; ++k) {
            float4 e4 = er[k];
            float4 x4 = *(const float4*)&xr[k * 4];
            dot = fmaf(x4.x, e4.x, dot);
            dot = fmaf(x4.y, e4.y, dot);
            dot = fmaf(x4.z, e4.z, dot);
            dot = fmaf(x4.w, e4.w, dot);
        }
        float v = esq[c] - 2.0f * dot;
        u64 pk = ((u64)f2key(v) << 32) | (unsigned)c;
        atomicMin(&rescueBuf[row], pk);
    }
}

// ---------------------------------------------------------------------------
// commit: unpack rescue winners into codes.
__global__ __launch_bounds__(256) void commit_kernel(
    const int* __restrict__ flagCnt, const int* __restrict__ flagRows,
    const u64* __restrict__ rescueBuf,
    int* __restrict__ codesI, float* __restrict__ codesF)
{
    int i = blockIdx.x * 256 + threadIdx.x;
    if (i < flagCnt[0]) {
        int row = flagRows[i];
        int code = (int)(unsigned)(rescueBuf[row] & 0xFFFFFFFFull);
        codesI[row] = code;
        codesF[row] = (float)code;
    }
}

// ---------------------------------------------------------------------------
// assign: gather quantize + STE, scatter counts/sums via fp32 atomics.
__global__ __launch_bounds__(256) void assign_kernel(
    const float* __restrict__ X, const float* __restrict__ E,
    const int* __restrict__ codesI,
    float* __restrict__ out_q,
    float* __restrict__ counts, float* __restrict__ sums)
{
    int t = blockIdx.x * 4 + (threadIdx.x >> 6);
    int lane = threadIdx.x & 63;
    int code = codesI[t];
    if (lane == 0) atomicAdd(&counts[code], 1.0f);
    float4 x = *(const float4*)&X[(size_t)t * DIM + lane * 4];
    float4 e = *(const float4*)&E[(size_t)code * DIM + lane * 4];
    float4 q;
    q.x = x.x + (e.x - x.x);
    q.y = x.y + (e.y - x.y);
    q.z = x.z + (e.z - x.z);
    q.w = x.w + (e.w - x.w);
    *(float4*)&out_q[(size_t)t * DIM + lane * 4] = q;
    float* s = &sums[(size_t)code * DIM + lane * 4];
    atomicAdd(s + 0, x.x);
    atomicAdd(s + 1, x.y);
    atomicAdd(s + 2, x.z);
    atomicAdd(s + 3, x.w);
}

// ---------------------------------------------------------------------------
__global__ __launch_bounds__(256) void finalize_kernel(
    const float* __restrict__ cs, const float* __restrict__ ea,
    const float* __restrict__ counts, const float* __restrict__ sums,
    float* __restrict__ out_embed, float* __restrict__ out_cs,
    float* __restrict__ out_ea)
{
    int vd = blockIdx.x * 256 + threadIdx.x;
    int v = vd >> 8, d = vd & 255;
    float cnt = counts[v];
    float ncs = cs[v] * 0.99f + cnt * 0.01f;
    float cb  = sums[vd] * (1.0f / 2048.0f);
    float nea = ea[vd] * 0.99f + cb * 0.01f;
    out_ea[vd] = nea;
    out_embed[vd] = nea / (ncs + 1e-5f);
    if (d == 0) out_cs[v] = ncs;
}

// ---------------------------------------------------------------------------
extern "C" void kernel_launch(void* const* d_in, const int* in_sizes, int n_in,
                              void* d_out, int out_size, void* d_ws, size_t ws_size,
                              hipStream_t stream)
{
    const float* input     = (const float*)d_in[0];
    const float* embed     = (const float*)d_in[1];
    const float* cluster   = (const float*)d_in[2];
    const float* embed_avg = (const float*)d_in[3];

    float* out = (float*)d_out;
    float* ws  = (float*)d_ws;

    float* esq      = ws + WS_ESQ;
    int*   codesI   = (int*)(ws + WS_CODESI);
    int*   flagRows = (int*)(ws + WS_FLAGROWS);
    float* candV    = ws + WS_CANDV;
    int*   candI    = (int*)(ws + WS_CANDI);
    float* candS    = ws + WS_CANDS;
    u16*   Xhi      = (u16*)(ws + WS_XHI);
    u16*   Xlo      = (u16*)(ws + WS_XLO);
    u16*   Ehi      = (u16*)(ws + WS_EHI);
    u16*   Elo      = (u16*)(ws + WS_ELO);
    float* counts   = ws + WS_COUNTS;
    float* sums     = ws + WS_SUMS;
    int*   flagCnt  = (int*)(ws + WS_FLAGCNT);
    u64*   rescueBuf= (u64*)(ws + WS_RESCUE);   // aliases dead Xhi

    hipMemsetAsync((char*)d_ws + WS_ZERO_OFF_BYTES, 0, WS_ZERO_BYTES, stream);

    prep_kernel<<<(M_TOK + VOC) / 4, 256, 0, stream>>>(
        input, embed, Xhi, Xlo, Ehi, Elo, esq);

    dim3 g1(M_TOK / BM, VOC / BN);
    mfma_argmin_kernel<<<g1, 256, 0, stream>>>(
        Xhi, Xlo, Ehi, Elo, esq, candV, candI, candS);

    reduce_kernel<<<M_TOK / 256, 256, 0, stream>>>(
        candV, candI, candS, codesI, out + OUT_C, flagCnt, flagRows, rescueBuf);

    rescue_kernel<<<512, 256, 0, stream>>>(
        input, embed, esq, flagCnt, flagRows, rescueBuf);

    commit_kernel<<<M_TOK / 256, 256, 0, stream>>>(
        flagCnt, flagRows, rescueBuf, codesI, out + OUT_C);

    assign_kernel<<<M_TOK / 4, 256, 0, stream>>>(
        input, embed, codesI, out + OUT_Q, counts, sums);

    finalize_kernel<<<(VOC * DIM) / 256, 256, 0, stream>>>(
        cluster, embed_avg, counts, sums,
        out + OUT_NE, out + OUT_NCS, out + OUT_NEA);
}